// Round 18
// baseline (916.283 us; speedup 1.0000x reference)
//
#include <hip/hip_runtime.h>
#include <math.h>

// Residual VQ, 4 stages, N=16384 rows, D=512, K=4096.
// Round 18: passA staging switched from reg-staging to global_load_lds
// (width 16) with pre-swizzled global source + XOR frag reads (rule #21:
// linear LDS dest, inverse-swizzled source, swizzled read). Fragment content
// is bit-identical to r17; only the staging path changes. m151 measured
// +35% for exactly this structure (646 -> 874 TF at 128^2/2-barrier).
// Everything else r17-verbatim (PASSED, 896us).
// Exact-math invariants (verified rounds 3-17): one fmaf per d, d=0..511
// ascending, per output; epilogue fl(fl(rsq-fl(2*dot))+cbsq) uncontracted;
// first-index ties; numpy pairwise rsq/cbsq tree; exact residual/q_ste chain.

namespace {
constexpr int N_ROWS     = 16384;
constexpr int DIM        = 512;
constexpr int K_CODES    = 4096;
constexpr int NUM_STAGES = 4;

constexpr int KTILES = 32;            // 128 codes per tile
constexpr float EPS  = 1e-3f;         // candidate margin (proven rounds 7-17)
constexpr int CAP    = 2;             // compacted candidates per (row,tile)

constexpr int CROWS  = 32;            // fallback passC rows per batch
constexpr int CGRIDY = 8;             // fallback passC y-blocks per ktile
constexpr int WSTRC  = 68;            // fallback passC Ws row stride (dwords)
constexpr int RSTR   = 68;            // fallback passC Rs row stride (dwords)

// d_out layout (all read back as float32):
constexpr size_t Q_OFF    = 0;
constexpr size_t IDX_OFF  = (size_t)N_ROWS * DIM;                  // 8388608
constexpr size_t LOSS_OFF = IDX_OFF + (size_t)N_ROWS * NUM_STAGES; // 8454144

// ws layout (bytes), total ~64.3 MB:
constexpr size_t RES_OFF  = 0;                                    // 32 MB fp32 residual
constexpr size_t RH_OFF   = (size_t)N_ROWS * DIM * 4;             // +16 MB bf16 residual
constexpr size_t WH_OFF   = RH_OFF + (size_t)N_ROWS * DIM * 2;    // +4 MB bf16 codebook
constexpr size_t CBSQ_OFF = WH_OFF + (size_t)K_CODES * DIM * 2;   // +16 KB
constexpr size_t RSQ_OFF  = CBSQ_OFF + (size_t)K_CODES * 4;       // +64 KB
constexpr size_t PART_OFF = RSQ_OFF + (size_t)N_ROWS * 4;         // +2 MB tile mins [tile][row]
constexpr size_t GBUF_OFF = PART_OFF + (size_t)N_ROWS * KTILES * 4;       // +8 MB [tile][row][CAP]
constexpr size_t BCNT_OFF = GBUF_OFF + (size_t)N_ROWS * KTILES * CAP * 8; // +128 B
constexpr size_t BENT_OFF = BCNT_OFF + 128;                       // +2 MB overflow lists
constexpr size_t BEST_OFF = BENT_OFF + (size_t)KTILES * N_ROWS * 4; // +128 KB packed best

constexpr unsigned long long EMPTY_E = 0xFFFFFFFFFFFFFFFFull;
constexpr unsigned long long OVFL_E  = 0xFFFFFFFFFFFFFFFEull;
} // namespace

typedef short bf16x8 __attribute__((ext_vector_type(8)));
typedef float f32x4  __attribute__((ext_vector_type(4)));

typedef __attribute__((address_space(1))) const unsigned int glob_u32;
typedef __attribute__((address_space(3))) unsigned int lds_u32;

__device__ __forceinline__ unsigned short f2bf(float x) {   // RNE fp32->bf16
    unsigned int u = __float_as_uint(x);
    return (unsigned short)((u + 0x7fffu + ((u >> 16) & 1u)) >> 16);
}

__device__ __forceinline__ float f4c(const float4& v, int q) {
    return q == 0 ? v.x : q == 1 ? v.y : q == 2 ? v.z : v.w;
}

// Register-based exact pairwise tree: v8[i] = row[lane + i*64], i=0..7.
__device__ __forceinline__ float rowsq_tree(const float v8[8], int lane) {
#pragma clang fp contract(off)
    float P[4];
#pragma unroll
    for (int b = 0; b < 4; ++b) {
        float xa = v8[2 * b];
        float xb = v8[2 * b + 1];
        float sa = xa * xa;
        float sb = xb * xb;
        float R  = sa + sb;
        float t  = R + __shfl_down(R, 16, 64);
        float u  = t + __shfl_down(t, 32, 64);
        float a  = u + __shfl_down(u, 8, 64);
        float c  = a + __shfl_down(a, 4, 64);
        float d  = c + __shfl_down(c, 2, 64);
        P[b]     = d + __shfl_down(d, 1, 64);
    }
    float s01 = P[0] + P[1];
    float s23 = P[2] + P[3];
    return s01 + s23;
}

// cbsq + codebook bf16 conversion, fused.
__global__ __launch_bounds__(64)
void cbsq_wh_kernel(const float* __restrict__ cb, float* __restrict__ cb_sq,
                    unsigned short* __restrict__ wh, float* __restrict__ loss) {
    int k = blockIdx.x;
    int lane = threadIdx.x;
    const float* row = cb + (size_t)k * DIM;
    unsigned short* whp = wh + (size_t)k * DIM;
    float v8[8];
#pragma unroll
    for (int i = 0; i < 8; ++i) {
        float v = row[lane + i * 64];
        v8[i] = v;
        whp[lane + i * 64] = f2bf(v);
    }
    float s = rowsq_tree(v8, lane);
    if (lane == 0) cb_sq[k] = s;
    if (k == 0 && lane == 0) *loss = 0.0f;
}

// Stage-0 init: rh = bf16(input), rsq = pairwise(input), zero bcnt.
__global__ __launch_bounds__(256)
void init_kernel(const float* __restrict__ input,
                 unsigned short* __restrict__ rh,
                 float* __restrict__ rsq, int* __restrict__ bcnt) {
    const int t = threadIdx.x;
    if (blockIdx.x == 0 && t < KTILES) bcnt[t] = 0;
    const int lane = t & 63;
    const int sub  = t >> 6;
    const int row  = blockIdx.x * 4 + sub;
    const float* x = input + (size_t)row * DIM;
    unsigned short* rhp = rh + (size_t)row * DIM;
    float v8[8];
#pragma unroll
    for (int i = 0; i < 8; ++i) {
        int d = lane + i * 64;
        float v = x[d];
        v8[i] = v;
        rhp[d] = f2bf(v);
    }
    float s = rowsq_tree(v8, lane);
    if (lane == 0) rsq[row] = s;
}

// Pass A: 128x128x(BK=64) bf16 MFMA GEMM + epilogue candidate compaction.
// Staging via global_load_lds width=16: linear LDS [row][64] bf16; global
// source pre-swizzled (lane loads granule (lane&7)^(lane>>3) of its row);
// frag reads XOR the slot with row&7 -> content identical to r17's layout.
__global__ __launch_bounds__(256, 2)
void passA_kernel(const unsigned short* __restrict__ rh,
                  const unsigned short* __restrict__ wh,
                  const float* __restrict__ cb_sq,
                  const float* __restrict__ rsq,
                  float* __restrict__ part,
                  unsigned long long* __restrict__ gbuf) {
    const int lin = blockIdx.x + KTILES * blockIdx.y;
    const int xcd = lin & 7;
    const int c   = lin >> 3;
    const int jb  = c & 31;                 // ktile
    const int mb  = xcd * 16 + (c >> 5);    // row tile: contiguous per XCD
    const int mbase = mb * 128;
    const int nbase = jb * 128;

    __shared__ __align__(16) unsigned short At[128 * 64];   // 16 KB linear
    __shared__ __align__(16) unsigned short Bt[128 * 64];   // 16 KB linear
    __shared__ float rowmin[128][2];

    const int t    = threadIdx.x;
    const int lane = t & 63;
    const int wid  = t >> 6;
    const int wr   = wid >> 1;
    const int wc   = wid & 1;

    // Staging geometry: wave wid owns rows [wid*32, wid*32+32) of A and B.
    // Per gload_lds: 64 lanes = 8 rows x 8 granules(16B). lane -> row-in-group
    // lrow = lane>>3, LDS slot = lane&7, global granule d8g = slot ^ lrow
    // (row&7 == lrow since bases are multiples of 8).
    const int lrow = lane >> 3;
    const int d8g  = (lane & 7) ^ lrow;

    f32x4 acc[4][4];
#pragma unroll
    for (int mi = 0; mi < 4; ++mi)
#pragma unroll
        for (int ni = 0; ni < 4; ++ni) acc[mi][ni] = (f32x4){0.f, 0.f, 0.f, 0.f};

    for (int k0 = 0; k0 < DIM; k0 += 64) {
#pragma unroll
        for (int i = 0; i < 4; ++i) {
            int rbase = wid * 32 + i * 8;
            int grow  = rbase + lrow;
            const unsigned short* ga =
                rh + (size_t)(mbase + grow) * DIM + k0 + d8g * 8;
            __builtin_amdgcn_global_load_lds(
                (glob_u32*)ga, (lds_u32*)&At[rbase * 64], 16, 0, 0);
            const unsigned short* gb =
                wh + (size_t)(nbase + grow) * DIM + k0 + d8g * 8;
            __builtin_amdgcn_global_load_lds(
                (glob_u32*)gb, (lds_u32*)&Bt[rbase * 64], 16, 0, 0);
        }
        __syncthreads();   // drains vmcnt before barrier (compiler-enforced)

#pragma unroll
        for (int kk = 0; kk < 2; ++kk) {
            bf16x8 af[4], bfr[4];
            const int g = kk * 4 + (lane >> 4);   // 16B granule wanted
#pragma unroll
            for (int mi = 0; mi < 4; ++mi) {
                int row = wr * 64 + mi * 16 + (lane & 15);
                af[mi] = *(const bf16x8*)&At[row * 64 + (g ^ (row & 7)) * 8];
            }
#pragma unroll
            for (int ni = 0; ni < 4; ++ni) {
                int row = wc * 64 + ni * 16 + (lane & 15);
                bfr[ni] = *(const bf16x8*)&Bt[row * 64 + (g ^ (row & 7)) * 8];
            }
#pragma unroll
            for (int mi = 0; mi < 4; ++mi)
#pragma unroll
                for (int ni = 0; ni < 4; ++ni)
                    acc[mi][ni] = __builtin_amdgcn_mfma_f32_16x16x32_bf16(
                        af[mi], bfr[ni], acc[mi][ni], 0, 0, 0);
        }
        __syncthreads();   // all reads done before next chunk overwrites
    }

    int* scnt = (int*)Bt;
    unsigned long long* sbuf = (unsigned long long*)At;
    if (t < 128) {
        scnt[t] = 0;
        sbuf[t * CAP + 0] = EMPTY_E;
        sbuf[t * CAP + 1] = EMPTY_E;
    }

    // Pass 1: per-row tile min.
#pragma unroll
    for (int mi = 0; mi < 4; ++mi) {
#pragma unroll
        for (int reg = 0; reg < 4; ++reg) {
            int rloc = wr * 64 + mi * 16 + (lane >> 4) * 4 + reg;
            float rsqv = rsq[mbase + rloc];
            float m = INFINITY;
#pragma unroll
            for (int ni = 0; ni < 4; ++ni) {
                int kg = nbase + wc * 64 + ni * 16 + (lane & 15);
                float y;
                {
#pragma clang fp contract(off)
                    float t2 = 2.0f * acc[mi][ni][reg];
                    float u  = rsqv - t2;
                    y        = u + cb_sq[kg];
                }
                m = fminf(m, y);
            }
#pragma unroll
            for (int off = 1; off < 16; off <<= 1)
                m = fminf(m, __shfl_xor(m, off, 64));
            if ((lane & 15) == 0) rowmin[rloc][wc] = m;
        }
    }
    __syncthreads();

    // Pass 2: compact candidates with y <= tilemin + EPS.
#pragma unroll
    for (int mi = 0; mi < 4; ++mi) {
#pragma unroll
        for (int reg = 0; reg < 4; ++reg) {
            int rloc = wr * 64 + mi * 16 + (lane >> 4) * 4 + reg;
            float thrT = fminf(rowmin[rloc][0], rowmin[rloc][1]) + EPS;
            float rsqv = rsq[mbase + rloc];
#pragma unroll
            for (int ni = 0; ni < 4; ++ni) {
                int kg = nbase + wc * 64 + ni * 16 + (lane & 15);
                float y;
                {
#pragma clang fp contract(off)
                    float t2 = 2.0f * acc[mi][ni][reg];
                    float u  = rsqv - t2;
                    y        = u + cb_sq[kg];
                }
                if (y <= thrT) {
                    int pos = atomicAdd(&scnt[rloc], 1);
                    if (pos < CAP)
                        sbuf[rloc * CAP + pos] =
                            ((unsigned long long)__float_as_uint(y) << 32) |
                            (unsigned)kg;
                }
            }
        }
    }
    __syncthreads();

    if (t < 128) {
        part[(size_t)jb * N_ROWS + (mbase + t)] =
            fminf(rowmin[t][0], rowmin[t][1]);
        unsigned long long s0 = sbuf[t * CAP + 0];
        unsigned long long s1 = sbuf[t * CAP + 1];
        if (scnt[t] > CAP) s0 = OVFL_E;
        size_t bidx = ((size_t)jb * N_ROWS + (mbase + t)) * CAP;
        gbuf[bidx]     = s0;
        gbuf[bidx + 1] = s1;
    }
}

// Pass BC: lane-per-(row,tile); width-32 min -> thr; count-1 shortcut; else
// inline exact chains + width-32 packed-u64 reduce. Overflow -> bent fallback.
__global__ __launch_bounds__(256)
void passBC_kernel(const float* __restrict__ res,
                   const float* __restrict__ cb,
                   const float* __restrict__ cb_sq,
                   const float* __restrict__ rsq,
                   const float* __restrict__ part,
                   const unsigned long long* __restrict__ gbuf,
                   int* __restrict__ bcnt, int* __restrict__ bent,
                   unsigned long long* __restrict__ best) {
    const int t   = threadIdx.x;
    const int jr  = t & 31;                  // tile index
    const int rs  = t >> 5;                  // 0..7
    const int row = blockIdx.x * 8 + rs;

    float pv = part[(size_t)jr * N_ROWS + row];
    float m = pv;
#pragma unroll
    for (int off = 1; off < 32; off <<= 1)
        m = fminf(m, __shfl_xor(m, off, 32));   // width 32: per-row group
    const float thr = m + EPS;

    unsigned long long s0 = EMPTY_E, s1 = EMPTY_E;
    bool surv = (pv <= thr);
    if (surv) {
        size_t bidx = ((size_t)jr * N_ROWS + row) * CAP;
        s0 = gbuf[bidx];
        s1 = gbuf[bidx + 1];
    }
    const bool ovfl = surv && (s0 == OVFL_E);
    if (ovfl) {                              // rare: full-tile fallback
        int pos = atomicAdd(&bcnt[jr], 1);
        bent[(size_t)jr * N_ROWS + pos] = row;
    }

    int lcl = 0;
    unsigned long long cand = EMPTY_E;
    float y0 = __uint_as_float((unsigned)(s0 >> 32));   // EMPTY/OVFL -> NaN
    float y1 = __uint_as_float((unsigned)(s1 >> 32));
    if (surv && !ovfl) {
        if (y0 <= thr) { lcl++; cand = s0; }
        if (y1 <= thr) { lcl++; cand = s1; }
    }
    int tot = lcl;
    int oc  = ovfl ? 1 : 0;
#pragma unroll
    for (int off = 1; off < 32; off <<= 1) {
        tot += __shfl_xor(tot, off, 32);
        oc  += __shfl_xor(oc, off, 32);
    }

    if (tot == 1 && oc == 0) {
        if (lcl == 1) best[row] = cand;      // unique candidate == argmin
        return;
    }

    float by = INFINITY; int bk = 0x7fffffff;
    if (surv && !ovfl && lcl > 0) {
        const float* rr  = res + (size_t)row * DIM;
        const float rsqv = rsq[row];
#pragma unroll
        for (int sl = 0; sl < CAP; ++sl) {
            unsigned long long s = sl ? s1 : s0;
            float yh = __uint_as_float((unsigned)(s >> 32));
            if (!(yh <= thr)) continue;      // EMPTY -> NaN -> skipped
            int k = (int)(s & 0xFFFFFFFFull);
            const float* wp = cb + (size_t)k * DIM;
            float dot = 0.0f;                // exact chain, d ascending
#pragma unroll 8
            for (int d = 0; d < DIM; d += 4) {
                float4 r4 = *(const float4*)(rr + d);
                float4 w4 = *(const float4*)(wp + d);
                dot = fmaf(r4.x, w4.x, dot);
                dot = fmaf(r4.y, w4.y, dot);
                dot = fmaf(r4.z, w4.z, dot);
                dot = fmaf(r4.w, w4.w, dot);
            }
            float y;
            {
#pragma clang fp contract(off)
                float t2 = 2.0f * dot;
                float u  = rsqv - t2;
                y        = u + cb_sq[k];
            }
            if (y < by || (y == by && k < bk)) { by = y; bk = k; }
        }
    }

    unsigned long long pk =
        ((unsigned long long)__float_as_uint(by) << 32) | (unsigned)bk;
#pragma unroll
    for (int off = 1; off < 32; off <<= 1) {
        unsigned long long o =
            (unsigned long long)__shfl_xor((long long)pk, off, 32);
        if (o < pk) pk = o;
    }
    if (jr == 0) best[row] = pk;   // plain store; passC atomicMins after
}

// Fallback pass C (round-13 verbatim): exact full-tile recheck of overflow
// entries (rare).
__global__ __launch_bounds__(256)
void passC_kernel(const float* __restrict__ res,
                  const float* __restrict__ cb,
                  const float* __restrict__ cb_sq,
                  const float* __restrict__ rsq,
                  const int* __restrict__ bcnt, const int* __restrict__ bent,
                  unsigned long long* __restrict__ best) {
    const int j   = blockIdx.x;
    const int cnt = bcnt[j];
    const int t   = threadIdx.x;
    const int cg  = t & 31;
    const int rg  = t >> 5;

    __shared__ __align__(16) float Ws[128 * WSTRC];
    __shared__ __align__(16) float Rs[CROWS * RSTR];
    __shared__ int   rowl[CROWS];
    __shared__ float rsql[CROWS];

    for (int base = blockIdx.y * CROWS; base < cnt; base += gridDim.y * CROWS) {
        if (t < CROWS) {
            int e  = base + t;
            int rw = bent[(size_t)j * N_ROWS + (e < cnt ? e : cnt - 1)];
            rowl[t] = rw;
            rsql[t] = rsq[rw];
        }
        __syncthreads();
        const int nrows = min(CROWS, cnt - base);

        float acc[4][4];
#pragma unroll
        for (int ri = 0; ri < 4; ++ri)
#pragma unroll
            for (int q = 0; q < 4; ++q) acc[ri][q] = 0.0f;

        for (int d0 = 0; d0 < DIM; d0 += 64) {
#pragma unroll
            for (int p = 0; p < 8; ++p) {
                int idx  = p * 256 + t;
                int cand = idx >> 4;
                int d4   = idx & 15;
                float4 v = *(const float4*)(cb + (size_t)(j * 128 + cand) * DIM + d0 + d4 * 4);
                int s = d4 ^ ((cand >> 2) & 7) ^ ((cand >> 5) & 3);
                *(float4*)&Ws[cand * WSTRC + s * 4] = v;
            }
#pragma unroll
            for (int p = 0; p < 2; ++p) {
                int idx = p * 256 + t;
                int row = idx >> 4;
                int d4  = idx & 15;
                float4 v = *(const float4*)(res + (size_t)rowl[row] * DIM + d0 + d4 * 4);
                *(float4*)&Rs[row * RSTR + d4 * 4] = v;
            }
            __syncthreads();

#pragma unroll
            for (int dq = 0; dq < 16; ++dq) {
                const int s = dq ^ (cg & 7) ^ ((cg >> 3) & 3);
                float4 w4[4];
#pragma unroll
                for (int q = 0; q < 4; ++q)
                    w4[q] = *(const float4*)&Ws[(cg * 4 + q) * WSTRC + s * 4];
#pragma unroll
                for (int ri = 0; ri < 4; ++ri) {
                    float4 rf = *(const float4*)&Rs[(rg * 4 + ri) * RSTR + dq * 4];
#pragma unroll
                    for (int dd = 0; dd < 4; ++dd) {
                        float rv = f4c(rf, dd);
                        acc[ri][0] = fmaf(rv, f4c(w4[0], dd), acc[ri][0]);
                        acc[ri][1] = fmaf(rv, f4c(w4[1], dd), acc[ri][1]);
                        acc[ri][2] = fmaf(rv, f4c(w4[2], dd), acc[ri][2]);
                        acc[ri][3] = fmaf(rv, f4c(w4[3], dd), acc[ri][3]);
                    }
                }
            }
            __syncthreads();
        }

#pragma unroll
        for (int ri = 0; ri < 4; ++ri) {
            int rloc = rg * 4 + ri;
            float rsqv = rsql[rloc];
            float by = INFINITY; int bk = 0x7fffffff;
#pragma unroll
            for (int q = 0; q < 4; ++q) {
                int k = j * 128 + cg * 4 + q;
                float y;
                {
#pragma clang fp contract(off)
                    float t2 = 2.0f * acc[ri][q];
                    float u  = rsqv - t2;
                    y        = u + cb_sq[k];
                }
                if (y < by || (y == by && k < bk)) { by = y; bk = k; }
            }
#pragma unroll
            for (int off = 1; off < 32; off <<= 1) {
                float ov = __shfl_xor(by, off, 64);
                int   oi = __shfl_xor(bk, off, 64);
                if (ov < by || (ov == by && oi < bk)) { by = ov; bk = oi; }
            }
            if (cg == 0 && rloc < nrows) {
                unsigned long long pk =
                    ((unsigned long long)__float_as_uint(by) << 32) |
                    (unsigned long long)(unsigned)bk;
                atomicMin(&best[rowl[rloc]], pk);
            }
        }
        __syncthreads();
    }
}

// Combine: best index -> idx_out; exact fp32 residual/q_ste update; for the
// next stage also emit rh, rsq, and zero bcnt.
__global__ __launch_bounds__(256)
void combine_kernel(float* __restrict__ res_out,
                    const float* __restrict__ res_in,
                    const float* __restrict__ cb,
                    const unsigned long long* __restrict__ best,
                    float* __restrict__ qout,
                    float* __restrict__ idx_out,
                    unsigned short* __restrict__ rh,
                    float* __restrict__ rsq,
                    int* __restrict__ bcnt,
                    int stage, int do_next) {
#pragma clang fp contract(off)
    const int t    = threadIdx.x;
    if (do_next && blockIdx.x == 0 && t < KTILES) bcnt[t] = 0;
    const int lane = t & 63;
    const int sub  = t >> 6;
    const int row  = blockIdx.x * 4 + sub;

    int bi = (int)(best[row] & 0xffffffffull);
    if (lane == 0) idx_out[(size_t)row * NUM_STAGES + stage] = (float)bi;

    const float* w   = cb + (size_t)bi * DIM;
    const float* rin = res_in + (size_t)row * DIM;
    float*       r   = res_out + (size_t)row * DIM;
    float*       q   = qout + (size_t)row * DIM;
    unsigned short* rhp = rh + (size_t)row * DIM;

    float rn8[8];
#pragma unroll
    for (int i = 0; i < DIM / 64; ++i) {
        int d = lane + i * 64;
        float wv = w[d];
        float rv = rin[d];
        float tq    = wv - rv;     // fl(q - r)
        float q_ste = rv + tq;     // fl(r + (q - r))
        float rn    = rv - q_ste;  // fl(r - q_ste)
        rn8[i] = rn;
        if (do_next) {
            r[d]   = rn;
            rhp[d] = f2bf(rn);
        }
        if (stage == 0) q[d] = q_ste;
        else            q[d] = q[d] + q_ste;
    }
    if (do_next) {
        float s = rowsq_tree(rn8, lane);
        if (lane == 0) rsq[row] = s;
    }
}

extern "C" void kernel_launch(void* const* d_in, const int* in_sizes, int n_in,
                              void* d_out, int out_size, void* d_ws, size_t ws_size,
                              hipStream_t stream) {
    const float* input = (const float*)d_in[0];
    const float* cb    = (const float*)d_in[1];

    float* out_f   = (float*)d_out;
    float* qout    = out_f + Q_OFF;
    float* idx_out = out_f + IDX_OFF;
    float* loss    = out_f + LOSS_OFF;

    char* ws = (char*)d_ws;
    float*          residual = (float*)(ws + RES_OFF);
    unsigned short* rh       = (unsigned short*)(ws + RH_OFF);
    unsigned short* wh       = (unsigned short*)(ws + WH_OFF);
    float*          cb_sq    = (float*)(ws + CBSQ_OFF);
    float*          rsq      = (float*)(ws + RSQ_OFF);
    float*          part     = (float*)(ws + PART_OFF);
    unsigned long long* gbuf = (unsigned long long*)(ws + GBUF_OFF);
    int*            bcnt     = (int*)(ws + BCNT_OFF);
    int*            bent     = (int*)(ws + BENT_OFF);
    unsigned long long* best = (unsigned long long*)(ws + BEST_OFF);

    cbsq_wh_kernel<<<K_CODES, 64, 0, stream>>>(cb, cb_sq, wh, loss);
    init_kernel<<<N_ROWS / 4, 256, 0, stream>>>(input, rh, rsq, bcnt);

    for (int s = 0; s < NUM_STAGES; ++s) {
        const float* rin = (s == 0) ? input : residual;
        passA_kernel<<<dim3(KTILES, N_ROWS / 128), 256, 0, stream>>>(
            rh, wh, cb_sq, rsq, part, gbuf);
        passBC_kernel<<<N_ROWS / 8, 256, 0, stream>>>(
            rin, cb, cb_sq, rsq, part, gbuf, bcnt, bent, best);
        passC_kernel<<<dim3(KTILES, CGRIDY), 256, 0, stream>>>(
            rin, cb, cb_sq, rsq, bcnt, bent, best);
        combine_kernel<<<N_ROWS / 4, 256, 0, stream>>>(
            residual, rin, cb, best, qout, idx_out, rh, rsq, bcnt,
            s, (s < NUM_STAGES - 1) ? 1 : 0);
    }
}

// Round 19
// 864.389 us; speedup vs baseline: 1.0600x; 1.0600x over previous
//
#include <hip/hip_runtime.h>
#include <math.h>

// Residual VQ, 4 stages, N=16384 rows, D=512, K=4096.
// Round 19: dispatch-graph collapse. passBC + passC + combine fused into ONE
// kernel (8 rows/block, 32 lanes/row): scan -> count-1 shortcut -> inline
// exact chains -> inline overflow full-tile recheck (ballot-driven) ->
// width-32 lex reduce -> fused residual/q_ste/rh/rsq update. 18 -> 10
// dispatches. passA is r18-verbatim (gload_lds + swizzle: conflicts 8.4e6
// -> 4.2e4, 104.7us).
// Exact-math invariants (verified rounds 3-18): one fmaf per d, d=0..511
// ascending, per output; epilogue fl(fl(rsq-fl(2*dot))+cbsq) uncontracted;
// first-index ties; numpy pairwise rsq/cbsq tree (32-lane mapping re-derived,
// identical fp32 op order); exact residual/q_ste chain.

namespace {
constexpr int N_ROWS     = 16384;
constexpr int DIM        = 512;
constexpr int K_CODES    = 4096;
constexpr int NUM_STAGES = 4;

constexpr int KTILES = 32;            // 128 codes per tile
constexpr float EPS  = 1e-3f;         // candidate margin (proven rounds 7-18)
constexpr int CAP    = 2;             // compacted candidates per (row,tile)

// d_out layout (all read back as float32):
constexpr size_t Q_OFF    = 0;
constexpr size_t IDX_OFF  = (size_t)N_ROWS * DIM;                  // 8388608
constexpr size_t LOSS_OFF = IDX_OFF + (size_t)N_ROWS * NUM_STAGES; // 8454144

// ws layout (bytes), total ~62.3 MB:
constexpr size_t RES_OFF  = 0;                                    // 32 MB fp32 residual
constexpr size_t RH_OFF   = (size_t)N_ROWS * DIM * 4;             // +16 MB bf16 residual
constexpr size_t WH_OFF   = RH_OFF + (size_t)N_ROWS * DIM * 2;    // +4 MB bf16 codebook
constexpr size_t CBSQ_OFF = WH_OFF + (size_t)K_CODES * DIM * 2;   // +16 KB
constexpr size_t RSQ_OFF  = CBSQ_OFF + (size_t)K_CODES * 4;       // +64 KB
constexpr size_t PART_OFF = RSQ_OFF + (size_t)N_ROWS * 4;         // +2 MB tile mins [tile][row]
constexpr size_t GBUF_OFF = PART_OFF + (size_t)N_ROWS * KTILES * 4; // +8 MB [tile][row][CAP]

constexpr unsigned long long EMPTY_E = 0xFFFFFFFFFFFFFFFFull;
constexpr unsigned long long OVFL_E  = 0xFFFFFFFFFFFFFFFEull;
} // namespace

typedef short bf16x8 __attribute__((ext_vector_type(8)));
typedef float f32x4  __attribute__((ext_vector_type(4)));

typedef __attribute__((address_space(1))) const unsigned int glob_u32;
typedef __attribute__((address_space(3))) unsigned int lds_u32;

__device__ __forceinline__ unsigned short f2bf(float x) {   // RNE fp32->bf16
    unsigned int u = __float_as_uint(x);
    return (unsigned short)((u + 0x7fffu + ((u >> 16) & 1u)) >> 16);
}

// Register-based exact pairwise tree (64-lane): v8[i] = row[lane + i*64].
__device__ __forceinline__ float rowsq_tree(const float v8[8], int lane) {
#pragma clang fp contract(off)
    float P[4];
#pragma unroll
    for (int b = 0; b < 4; ++b) {
        float xa = v8[2 * b];
        float xb = v8[2 * b + 1];
        float sa = xa * xa;
        float sb = xb * xb;
        float R  = sa + sb;
        float t  = R + __shfl_down(R, 16, 64);
        float u  = t + __shfl_down(t, 32, 64);
        float a  = u + __shfl_down(u, 8, 64);
        float c  = a + __shfl_down(a, 4, 64);
        float d  = c + __shfl_down(c, 2, 64);
        P[b]     = d + __shfl_down(d, 1, 64);
    }
    float s01 = P[0] + P[1];
    float s23 = P[2] + P[3];
    return s01 + s23;
}

// cbsq + codebook bf16 conversion, fused.
__global__ __launch_bounds__(64)
void cbsq_wh_kernel(const float* __restrict__ cb, float* __restrict__ cb_sq,
                    unsigned short* __restrict__ wh, float* __restrict__ loss) {
    int k = blockIdx.x;
    int lane = threadIdx.x;
    const float* row = cb + (size_t)k * DIM;
    unsigned short* whp = wh + (size_t)k * DIM;
    float v8[8];
#pragma unroll
    for (int i = 0; i < 8; ++i) {
        float v = row[lane + i * 64];
        v8[i] = v;
        whp[lane + i * 64] = f2bf(v);
    }
    float s = rowsq_tree(v8, lane);
    if (lane == 0) cb_sq[k] = s;
    if (k == 0 && lane == 0) *loss = 0.0f;
}

// Stage-0 init: rh = bf16(input), rsq = pairwise(input).
__global__ __launch_bounds__(256)
void init_kernel(const float* __restrict__ input,
                 unsigned short* __restrict__ rh,
                 float* __restrict__ rsq) {
    const int t = threadIdx.x;
    const int lane = t & 63;
    const int sub  = t >> 6;
    const int row  = blockIdx.x * 4 + sub;
    const float* x = input + (size_t)row * DIM;
    unsigned short* rhp = rh + (size_t)row * DIM;
    float v8[8];
#pragma unroll
    for (int i = 0; i < 8; ++i) {
        int d = lane + i * 64;
        float v = x[d];
        v8[i] = v;
        rhp[d] = f2bf(v);
    }
    float s = rowsq_tree(v8, lane);
    if (lane == 0) rsq[row] = s;
}

// Pass A (r18-verbatim): 128x128x(BK=64) bf16 MFMA GEMM via global_load_lds
// with pre-swizzled source + XOR frag reads; epilogue candidate compaction.
__global__ __launch_bounds__(256, 2)
void passA_kernel(const unsigned short* __restrict__ rh,
                  const unsigned short* __restrict__ wh,
                  const float* __restrict__ cb_sq,
                  const float* __restrict__ rsq,
                  float* __restrict__ part,
                  unsigned long long* __restrict__ gbuf) {
    const int lin = blockIdx.x + KTILES * blockIdx.y;
    const int xcd = lin & 7;
    const int c   = lin >> 3;
    const int jb  = c & 31;
    const int mb  = xcd * 16 + (c >> 5);
    const int mbase = mb * 128;
    const int nbase = jb * 128;

    __shared__ __align__(16) unsigned short At[128 * 64];
    __shared__ __align__(16) unsigned short Bt[128 * 64];
    __shared__ float rowmin[128][2];

    const int t    = threadIdx.x;
    const int lane = t & 63;
    const int wid  = t >> 6;
    const int wr   = wid >> 1;
    const int wc   = wid & 1;

    const int lrow = lane >> 3;
    const int d8g  = (lane & 7) ^ lrow;

    f32x4 acc[4][4];
#pragma unroll
    for (int mi = 0; mi < 4; ++mi)
#pragma unroll
        for (int ni = 0; ni < 4; ++ni) acc[mi][ni] = (f32x4){0.f, 0.f, 0.f, 0.f};

    for (int k0 = 0; k0 < DIM; k0 += 64) {
#pragma unroll
        for (int i = 0; i < 4; ++i) {
            int rbase = wid * 32 + i * 8;
            int grow  = rbase + lrow;
            const unsigned short* ga =
                rh + (size_t)(mbase + grow) * DIM + k0 + d8g * 8;
            __builtin_amdgcn_global_load_lds(
                (glob_u32*)ga, (lds_u32*)&At[rbase * 64], 16, 0, 0);
            const unsigned short* gb =
                wh + (size_t)(nbase + grow) * DIM + k0 + d8g * 8;
            __builtin_amdgcn_global_load_lds(
                (glob_u32*)gb, (lds_u32*)&Bt[rbase * 64], 16, 0, 0);
        }
        __syncthreads();

#pragma unroll
        for (int kk = 0; kk < 2; ++kk) {
            bf16x8 af[4], bfr[4];
            const int g = kk * 4 + (lane >> 4);
#pragma unroll
            for (int mi = 0; mi < 4; ++mi) {
                int row = wr * 64 + mi * 16 + (lane & 15);
                af[mi] = *(const bf16x8*)&At[row * 64 + (g ^ (row & 7)) * 8];
            }
#pragma unroll
            for (int ni = 0; ni < 4; ++ni) {
                int row = wc * 64 + ni * 16 + (lane & 15);
                bfr[ni] = *(const bf16x8*)&Bt[row * 64 + (g ^ (row & 7)) * 8];
            }
#pragma unroll
            for (int mi = 0; mi < 4; ++mi)
#pragma unroll
                for (int ni = 0; ni < 4; ++ni)
                    acc[mi][ni] = __builtin_amdgcn_mfma_f32_16x16x32_bf16(
                        af[mi], bfr[ni], acc[mi][ni], 0, 0, 0);
        }
        __syncthreads();
    }

    int* scnt = (int*)Bt;
    unsigned long long* sbuf = (unsigned long long*)At;
    if (t < 128) {
        scnt[t] = 0;
        sbuf[t * CAP + 0] = EMPTY_E;
        sbuf[t * CAP + 1] = EMPTY_E;
    }

    // Pass 1: per-row tile min.
#pragma unroll
    for (int mi = 0; mi < 4; ++mi) {
#pragma unroll
        for (int reg = 0; reg < 4; ++reg) {
            int rloc = wr * 64 + mi * 16 + (lane >> 4) * 4 + reg;
            float rsqv = rsq[mbase + rloc];
            float m = INFINITY;
#pragma unroll
            for (int ni = 0; ni < 4; ++ni) {
                int kg = nbase + wc * 64 + ni * 16 + (lane & 15);
                float y;
                {
#pragma clang fp contract(off)
                    float t2 = 2.0f * acc[mi][ni][reg];
                    float u  = rsqv - t2;
                    y        = u + cb_sq[kg];
                }
                m = fminf(m, y);
            }
#pragma unroll
            for (int off = 1; off < 16; off <<= 1)
                m = fminf(m, __shfl_xor(m, off, 64));
            if ((lane & 15) == 0) rowmin[rloc][wc] = m;
        }
    }
    __syncthreads();

    // Pass 2: compact candidates with y <= tilemin + EPS.
#pragma unroll
    for (int mi = 0; mi < 4; ++mi) {
#pragma unroll
        for (int reg = 0; reg < 4; ++reg) {
            int rloc = wr * 64 + mi * 16 + (lane >> 4) * 4 + reg;
            float thrT = fminf(rowmin[rloc][0], rowmin[rloc][1]) + EPS;
            float rsqv = rsq[mbase + rloc];
#pragma unroll
            for (int ni = 0; ni < 4; ++ni) {
                int kg = nbase + wc * 64 + ni * 16 + (lane & 15);
                float y;
                {
#pragma clang fp contract(off)
                    float t2 = 2.0f * acc[mi][ni][reg];
                    float u  = rsqv - t2;
                    y        = u + cb_sq[kg];
                }
                if (y <= thrT) {
                    int pos = atomicAdd(&scnt[rloc], 1);
                    if (pos < CAP)
                        sbuf[rloc * CAP + pos] =
                            ((unsigned long long)__float_as_uint(y) << 32) |
                            (unsigned)kg;
                }
            }
        }
    }
    __syncthreads();

    if (t < 128) {
        part[(size_t)jb * N_ROWS + (mbase + t)] =
            fminf(rowmin[t][0], rowmin[t][1]);
        unsigned long long s0 = sbuf[t * CAP + 0];
        unsigned long long s1 = sbuf[t * CAP + 1];
        if (scnt[t] > CAP) s0 = OVFL_E;
        size_t bidx = ((size_t)jb * N_ROWS + (mbase + t)) * CAP;
        gbuf[bidx]     = s0;
        gbuf[bidx + 1] = s1;
    }
}

// Fused finish: per row (32 lanes): thr scan -> count-1 shortcut -> inline
// exact chains -> inline overflow full-tile recheck -> width-32 lex reduce
// (all lanes get best) -> residual/q_ste/rh/rsq update.
__global__ __launch_bounds__(256)
void finish_kernel(float* __restrict__ res,        // residual out (in-place ok)
                   const float* __restrict__ rin,  // residual in (= input at s0)
                   const float* __restrict__ cb,
                   const float* __restrict__ cb_sq,
                   float* __restrict__ rsq,        // in: this stage; out: next
                   const float* __restrict__ part,
                   const unsigned long long* __restrict__ gbuf,
                   float* __restrict__ qout,
                   float* __restrict__ idx_out,
                   unsigned short* __restrict__ rh,
                   int stage, int do_next) {
#pragma clang fp contract(off)
    const int t   = threadIdx.x;
    const int jr  = t & 31;                  // tile index / lane-in-group
    const int rs  = t >> 5;                  // 0..7
    const int row = blockIdx.x * 8 + rs;

    float pv = part[(size_t)jr * N_ROWS + row];
    float m = pv;
#pragma unroll
    for (int off = 1; off < 32; off <<= 1)
        m = fminf(m, __shfl_xor(m, off, 32));
    const float thr = m + EPS;

    unsigned long long s0 = EMPTY_E, s1 = EMPTY_E;
    bool surv = (pv <= thr);
    if (surv) {
        size_t bidx = ((size_t)jr * N_ROWS + row) * CAP;
        s0 = gbuf[bidx];
        s1 = gbuf[bidx + 1];
    }
    const bool ovfl = surv && (s0 == OVFL_E);

    int lcl = 0;
    unsigned long long cand = EMPTY_E;
    float y0 = __uint_as_float((unsigned)(s0 >> 32));   // EMPTY/OVFL -> NaN
    float y1 = __uint_as_float((unsigned)(s1 >> 32));
    if (surv && !ovfl) {
        if (y0 <= thr) { lcl++; cand = s0; }
        if (y1 <= thr) { lcl++; cand = s1; }
    }
    int tot = lcl;
    int oc  = ovfl ? 1 : 0;
#pragma unroll
    for (int off = 1; off < 32; off <<= 1) {
        tot += __shfl_xor(tot, off, 32);
        oc  += __shfl_xor(oc, off, 32);
    }

    const float* rr  = rin + (size_t)row * DIM;
    const float rsqv = rsq[row];

    unsigned long long lpk;
    if (tot == 1 && oc == 0) {
        lpk = (lcl == 1) ? cand : EMPTY_E;   // unique candidate == argmin
    } else {
        float by = INFINITY; int bk = 0x7fffffff;
        if (surv && !ovfl && lcl > 0) {
#pragma unroll
            for (int sl = 0; sl < CAP; ++sl) {
                unsigned long long s = sl ? s1 : s0;
                float yh = __uint_as_float((unsigned)(s >> 32));
                if (!(yh <= thr)) continue;  // EMPTY -> NaN -> skipped
                int k = (int)(s & 0xFFFFFFFFull);
                const float* wp = cb + (size_t)k * DIM;
                float dot = 0.0f;            // exact chain, d ascending
#pragma unroll 8
                for (int d = 0; d < DIM; d += 4) {
                    float4 r4 = *(const float4*)(rr + d);
                    float4 w4 = *(const float4*)(wp + d);
                    dot = fmaf(r4.x, w4.x, dot);
                    dot = fmaf(r4.y, w4.y, dot);
                    dot = fmaf(r4.z, w4.z, dot);
                    dot = fmaf(r4.w, w4.w, dot);
                }
                float t2 = 2.0f * dot;
                float u  = rsqv - t2;
                float y  = u + cb_sq[k];
                if (y < by || (y == by && k < bk)) { by = y; bk = k; }
            }
        }
        // Overflow tiles: full-tile exact recheck by the whole 32-lane group.
        unsigned grp = (unsigned)(__ballot(ovfl) >> (t & 32));
        while (grp) {
            int jt = __builtin_ctz(grp);
            grp &= grp - 1;
#pragma unroll
            for (int q = 0; q < 4; ++q) {
                int k = jt * 128 + jr * 4 + q;
                const float* wp = cb + (size_t)k * DIM;
                float dot = 0.0f;            // exact chain, d ascending
#pragma unroll 8
                for (int d = 0; d < DIM; d += 4) {
                    float4 r4 = *(const float4*)(rr + d);
                    float4 w4 = *(const float4*)(wp + d);
                    dot = fmaf(r4.x, w4.x, dot);
                    dot = fmaf(r4.y, w4.y, dot);
                    dot = fmaf(r4.z, w4.z, dot);
                    dot = fmaf(r4.w, w4.w, dot);
                }
                float t2 = 2.0f * dot;
                float u  = rsqv - t2;
                float y  = u + cb_sq[k];
                if (y < by || (y == by && k < bk)) { by = y; bk = k; }
            }
        }
        lpk = ((unsigned long long)__float_as_uint(by) << 32) | (unsigned)bk;
    }

    // Width-32 lexicographic min; butterfly -> ALL lanes hold the result.
#pragma unroll
    for (int off = 1; off < 32; off <<= 1) {
        unsigned long long o =
            (unsigned long long)__shfl_xor((long long)lpk, off, 32);
        if (o < lpk) lpk = o;
    }
    const int bi = (int)(lpk & 0xFFFFFFFFull);
    if (jr == 0) idx_out[(size_t)row * NUM_STAGES + stage] = (float)bi;

    // Fused combine: lane jr owns elements d = jr + 32*i (i = 0..15).
    const float* wp = cb + (size_t)bi * DIM;
    float*       rp = res + (size_t)row * DIM;
    float*       qp = qout + (size_t)row * DIM;
    unsigned short* rhp = rh + (size_t)row * DIM;

    float rn16[16];
#pragma unroll
    for (int i = 0; i < 16; ++i) {
        int d = jr + 32 * i;
        float wv = wp[d];
        float rv = rr[d];
        float tq    = wv - rv;     // fl(q - r)
        float q_ste = rv + tq;     // fl(r + (q - r))
        float rn    = rv - q_ste;  // fl(r - q_ste)
        rn16[i] = rn;
        if (do_next) {
            rp[d]  = rn;
            rhp[d] = f2bf(rn);
        }
        if (stage == 0) qp[d] = q_ste;
        else            qp[d] = qp[d] + q_ste;   // stage-order accumulation
    }

    if (do_next) {
        // 32-lane numpy pairwise tree; element mapping lane+32i reproduces
        // R_j (j=0..3) and the exact 64-lane fp32 addition order:
        //   R_lo = R_{lane>>4},  R_hi = R_{(lane>>4)+2}
        //   u = (R0+R1) + (R2+R3) on lanes 0..15, then +8/+4/+2/+1.
        float P[4];
#pragma unroll
        for (int b = 0; b < 4; ++b) {
            float xa_lo = rn16[4 * b + 0];   // rel b*128 + lane
            float xb_lo = rn16[4 * b + 2];   // rel b*128 + 64 + lane
            float xa_hi = rn16[4 * b + 1];   // rel b*128 + 32 + lane
            float xb_hi = rn16[4 * b + 3];   // rel b*128 + 96 + lane
            float sa_lo = xa_lo * xa_lo;
            float sb_lo = xb_lo * xb_lo;
            float R_lo  = sa_lo + sb_lo;
            float sa_hi = xa_hi * xa_hi;
            float sb_hi = xb_hi * xb_hi;
            float R_hi  = sa_hi + sb_hi;
            float t_lo = R_lo + __shfl_down(R_lo, 16, 32);  // R0+R1 (lanes 0..15)
            float t_hi = R_hi + __shfl_down(R_hi, 16, 32);  // R2+R3
            float u  = t_lo + t_hi;
            float a  = u + __shfl_down(u, 8, 32);
            float cc = a + __shfl_down(a, 4, 32);
            float dd = cc + __shfl_down(cc, 2, 32);
            P[b]     = dd + __shfl_down(dd, 1, 32);
        }
        float s01 = P[0] + P[1];
        float s23 = P[2] + P[3];
        if (jr == 0) rsq[row] = s01 + s23;
    }
}

extern "C" void kernel_launch(void* const* d_in, const int* in_sizes, int n_in,
                              void* d_out, int out_size, void* d_ws, size_t ws_size,
                              hipStream_t stream) {
    const float* input = (const float*)d_in[0];
    const float* cb    = (const float*)d_in[1];

    float* out_f   = (float*)d_out;
    float* qout    = out_f + Q_OFF;
    float* idx_out = out_f + IDX_OFF;
    float* loss    = out_f + LOSS_OFF;

    char* ws = (char*)d_ws;
    float*          residual = (float*)(ws + RES_OFF);
    unsigned short* rh       = (unsigned short*)(ws + RH_OFF);
    unsigned short* wh       = (unsigned short*)(ws + WH_OFF);
    float*          cb_sq    = (float*)(ws + CBSQ_OFF);
    float*          rsq      = (float*)(ws + RSQ_OFF);
    float*          part     = (float*)(ws + PART_OFF);
    unsigned long long* gbuf = (unsigned long long*)(ws + GBUF_OFF);

    cbsq_wh_kernel<<<K_CODES, 64, 0, stream>>>(cb, cb_sq, wh, loss);
    init_kernel<<<N_ROWS / 4, 256, 0, stream>>>(input, rh, rsq);

    for (int s = 0; s < NUM_STAGES; ++s) {
        const float* rin = (s == 0) ? input : residual;
        passA_kernel<<<dim3(KTILES, N_ROWS / 128), 256, 0, stream>>>(
            rh, wh, cb_sq, rsq, part, gbuf);
        finish_kernel<<<N_ROWS / 8, 256, 0, stream>>>(
            residual, rin, cb, cb_sq, rsq, part, gbuf,
            qout, idx_out, rh, s, (s < NUM_STAGES - 1) ? 1 : 0);
    }
}

// Round 20
// 851.023 us; speedup vs baseline: 1.0767x; 1.0157x over previous
//
#include <hip/hip_runtime.h>
#include <math.h>

// Residual VQ, 4 stages, N=16384 rows, D=512, K=4096.
// Round 20: finish_kernel combine vectorized to float4 (was 16 scalar-4B
// iterations -> latency-bound at 1.38 TB/s, VALUBusy 8.3%). New ownership
// map d = 4*jr + 128*i; rsq pairwise tree re-derived for this map (addition
// DAG node-identical to the verified 64-lane tree: shfl distances 16/4/8/2/1
// lanes = l-distances 64/16/32/8/4/2/1). passA r18-verbatim; rest r19.
// Exact-math invariants (verified rounds 3-19): one fmaf per d, d=0..511
// ascending, per output; epilogue fl(fl(rsq-fl(2*dot))+cbsq) uncontracted;
// first-index ties; numpy pairwise rsq/cbsq tree; exact residual/q_ste chain.

namespace {
constexpr int N_ROWS     = 16384;
constexpr int DIM        = 512;
constexpr int K_CODES    = 4096;
constexpr int NUM_STAGES = 4;

constexpr int KTILES = 32;            // 128 codes per tile
constexpr float EPS  = 1e-3f;         // candidate margin (proven rounds 7-19)
constexpr int CAP    = 2;             // compacted candidates per (row,tile)

// d_out layout (all read back as float32):
constexpr size_t Q_OFF    = 0;
constexpr size_t IDX_OFF  = (size_t)N_ROWS * DIM;                  // 8388608
constexpr size_t LOSS_OFF = IDX_OFF + (size_t)N_ROWS * NUM_STAGES; // 8454144

// ws layout (bytes), total ~62.3 MB:
constexpr size_t RES_OFF  = 0;                                    // 32 MB fp32 residual
constexpr size_t RH_OFF   = (size_t)N_ROWS * DIM * 4;             // +16 MB bf16 residual
constexpr size_t WH_OFF   = RH_OFF + (size_t)N_ROWS * DIM * 2;    // +4 MB bf16 codebook
constexpr size_t CBSQ_OFF = WH_OFF + (size_t)K_CODES * DIM * 2;   // +16 KB
constexpr size_t RSQ_OFF  = CBSQ_OFF + (size_t)K_CODES * 4;       // +64 KB
constexpr size_t PART_OFF = RSQ_OFF + (size_t)N_ROWS * 4;         // +2 MB tile mins [tile][row]
constexpr size_t GBUF_OFF = PART_OFF + (size_t)N_ROWS * KTILES * 4; // +8 MB [tile][row][CAP]

constexpr unsigned long long EMPTY_E = 0xFFFFFFFFFFFFFFFFull;
constexpr unsigned long long OVFL_E  = 0xFFFFFFFFFFFFFFFEull;
} // namespace

typedef short bf16x8 __attribute__((ext_vector_type(8)));
typedef float f32x4  __attribute__((ext_vector_type(4)));

typedef __attribute__((address_space(1))) const unsigned int glob_u32;
typedef __attribute__((address_space(3))) unsigned int lds_u32;

__device__ __forceinline__ unsigned short f2bf(float x) {   // RNE fp32->bf16
    unsigned int u = __float_as_uint(x);
    return (unsigned short)((u + 0x7fffu + ((u >> 16) & 1u)) >> 16);
}

// Register-based exact pairwise tree (64-lane): v8[i] = row[lane + i*64].
__device__ __forceinline__ float rowsq_tree(const float v8[8], int lane) {
#pragma clang fp contract(off)
    float P[4];
#pragma unroll
    for (int b = 0; b < 4; ++b) {
        float xa = v8[2 * b];
        float xb = v8[2 * b + 1];
        float sa = xa * xa;
        float sb = xb * xb;
        float R  = sa + sb;
        float t  = R + __shfl_down(R, 16, 64);
        float u  = t + __shfl_down(t, 32, 64);
        float a  = u + __shfl_down(u, 8, 64);
        float c  = a + __shfl_down(a, 4, 64);
        float d  = c + __shfl_down(c, 2, 64);
        P[b]     = d + __shfl_down(d, 1, 64);
    }
    float s01 = P[0] + P[1];
    float s23 = P[2] + P[3];
    return s01 + s23;
}

// cbsq + codebook bf16 conversion, fused.
__global__ __launch_bounds__(64)
void cbsq_wh_kernel(const float* __restrict__ cb, float* __restrict__ cb_sq,
                    unsigned short* __restrict__ wh, float* __restrict__ loss) {
    int k = blockIdx.x;
    int lane = threadIdx.x;
    const float* row = cb + (size_t)k * DIM;
    unsigned short* whp = wh + (size_t)k * DIM;
    float v8[8];
#pragma unroll
    for (int i = 0; i < 8; ++i) {
        float v = row[lane + i * 64];
        v8[i] = v;
        whp[lane + i * 64] = f2bf(v);
    }
    float s = rowsq_tree(v8, lane);
    if (lane == 0) cb_sq[k] = s;
    if (k == 0 && lane == 0) *loss = 0.0f;
}

// Stage-0 init: rh = bf16(input), rsq = pairwise(input).
__global__ __launch_bounds__(256)
void init_kernel(const float* __restrict__ input,
                 unsigned short* __restrict__ rh,
                 float* __restrict__ rsq) {
    const int t = threadIdx.x;
    const int lane = t & 63;
    const int sub  = t >> 6;
    const int row  = blockIdx.x * 4 + sub;
    const float* x = input + (size_t)row * DIM;
    unsigned short* rhp = rh + (size_t)row * DIM;
    float v8[8];
#pragma unroll
    for (int i = 0; i < 8; ++i) {
        int d = lane + i * 64;
        float v = x[d];
        v8[i] = v;
        rhp[d] = f2bf(v);
    }
    float s = rowsq_tree(v8, lane);
    if (lane == 0) rsq[row] = s;
}

// Pass A (r18-verbatim): 128x128x(BK=64) bf16 MFMA GEMM via global_load_lds
// with pre-swizzled source + XOR frag reads; epilogue candidate compaction.
__global__ __launch_bounds__(256, 2)
void passA_kernel(const unsigned short* __restrict__ rh,
                  const unsigned short* __restrict__ wh,
                  const float* __restrict__ cb_sq,
                  const float* __restrict__ rsq,
                  float* __restrict__ part,
                  unsigned long long* __restrict__ gbuf) {
    const int lin = blockIdx.x + KTILES * blockIdx.y;
    const int xcd = lin & 7;
    const int c   = lin >> 3;
    const int jb  = c & 31;
    const int mb  = xcd * 16 + (c >> 5);
    const int mbase = mb * 128;
    const int nbase = jb * 128;

    __shared__ __align__(16) unsigned short At[128 * 64];
    __shared__ __align__(16) unsigned short Bt[128 * 64];
    __shared__ float rowmin[128][2];

    const int t    = threadIdx.x;
    const int lane = t & 63;
    const int wid  = t >> 6;
    const int wr   = wid >> 1;
    const int wc   = wid & 1;

    const int lrow = lane >> 3;
    const int d8g  = (lane & 7) ^ lrow;

    f32x4 acc[4][4];
#pragma unroll
    for (int mi = 0; mi < 4; ++mi)
#pragma unroll
        for (int ni = 0; ni < 4; ++ni) acc[mi][ni] = (f32x4){0.f, 0.f, 0.f, 0.f};

    for (int k0 = 0; k0 < DIM; k0 += 64) {
#pragma unroll
        for (int i = 0; i < 4; ++i) {
            int rbase = wid * 32 + i * 8;
            int grow  = rbase + lrow;
            const unsigned short* ga =
                rh + (size_t)(mbase + grow) * DIM + k0 + d8g * 8;
            __builtin_amdgcn_global_load_lds(
                (glob_u32*)ga, (lds_u32*)&At[rbase * 64], 16, 0, 0);
            const unsigned short* gb =
                wh + (size_t)(nbase + grow) * DIM + k0 + d8g * 8;
            __builtin_amdgcn_global_load_lds(
                (glob_u32*)gb, (lds_u32*)&Bt[rbase * 64], 16, 0, 0);
        }
        __syncthreads();

#pragma unroll
        for (int kk = 0; kk < 2; ++kk) {
            bf16x8 af[4], bfr[4];
            const int g = kk * 4 + (lane >> 4);
#pragma unroll
            for (int mi = 0; mi < 4; ++mi) {
                int row = wr * 64 + mi * 16 + (lane & 15);
                af[mi] = *(const bf16x8*)&At[row * 64 + (g ^ (row & 7)) * 8];
            }
#pragma unroll
            for (int ni = 0; ni < 4; ++ni) {
                int row = wc * 64 + ni * 16 + (lane & 15);
                bfr[ni] = *(const bf16x8*)&Bt[row * 64 + (g ^ (row & 7)) * 8];
            }
#pragma unroll
            for (int mi = 0; mi < 4; ++mi)
#pragma unroll
                for (int ni = 0; ni < 4; ++ni)
                    acc[mi][ni] = __builtin_amdgcn_mfma_f32_16x16x32_bf16(
                        af[mi], bfr[ni], acc[mi][ni], 0, 0, 0);
        }
        __syncthreads();
    }

    int* scnt = (int*)Bt;
    unsigned long long* sbuf = (unsigned long long*)At;
    if (t < 128) {
        scnt[t] = 0;
        sbuf[t * CAP + 0] = EMPTY_E;
        sbuf[t * CAP + 1] = EMPTY_E;
    }

    // Pass 1: per-row tile min.
#pragma unroll
    for (int mi = 0; mi < 4; ++mi) {
#pragma unroll
        for (int reg = 0; reg < 4; ++reg) {
            int rloc = wr * 64 + mi * 16 + (lane >> 4) * 4 + reg;
            float rsqv = rsq[mbase + rloc];
            float m = INFINITY;
#pragma unroll
            for (int ni = 0; ni < 4; ++ni) {
                int kg = nbase + wc * 64 + ni * 16 + (lane & 15);
                float y;
                {
#pragma clang fp contract(off)
                    float t2 = 2.0f * acc[mi][ni][reg];
                    float u  = rsqv - t2;
                    y        = u + cb_sq[kg];
                }
                m = fminf(m, y);
            }
#pragma unroll
            for (int off = 1; off < 16; off <<= 1)
                m = fminf(m, __shfl_xor(m, off, 64));
            if ((lane & 15) == 0) rowmin[rloc][wc] = m;
        }
    }
    __syncthreads();

    // Pass 2: compact candidates with y <= tilemin + EPS.
#pragma unroll
    for (int mi = 0; mi < 4; ++mi) {
#pragma unroll
        for (int reg = 0; reg < 4; ++reg) {
            int rloc = wr * 64 + mi * 16 + (lane >> 4) * 4 + reg;
            float thrT = fminf(rowmin[rloc][0], rowmin[rloc][1]) + EPS;
            float rsqv = rsq[mbase + rloc];
#pragma unroll
            for (int ni = 0; ni < 4; ++ni) {
                int kg = nbase + wc * 64 + ni * 16 + (lane & 15);
                float y;
                {
#pragma clang fp contract(off)
                    float t2 = 2.0f * acc[mi][ni][reg];
                    float u  = rsqv - t2;
                    y        = u + cb_sq[kg];
                }
                if (y <= thrT) {
                    int pos = atomicAdd(&scnt[rloc], 1);
                    if (pos < CAP)
                        sbuf[rloc * CAP + pos] =
                            ((unsigned long long)__float_as_uint(y) << 32) |
                            (unsigned)kg;
                }
            }
        }
    }
    __syncthreads();

    if (t < 128) {
        part[(size_t)jb * N_ROWS + (mbase + t)] =
            fminf(rowmin[t][0], rowmin[t][1]);
        unsigned long long s0 = sbuf[t * CAP + 0];
        unsigned long long s1 = sbuf[t * CAP + 1];
        if (scnt[t] > CAP) s0 = OVFL_E;
        size_t bidx = ((size_t)jb * N_ROWS + (mbase + t)) * CAP;
        gbuf[bidx]     = s0;
        gbuf[bidx + 1] = s1;
    }
}

// Fused finish (float4 combine): per row (32 lanes): thr scan -> count-1
// shortcut -> inline exact chains -> inline overflow full-tile recheck ->
// width-32 lex reduce -> vectorized residual/q_ste/rh/rsq update.
// Lane jr owns float4 at d = 4*jr + 128*i, i = 0..3.
__global__ __launch_bounds__(256)
void finish_kernel(float* __restrict__ res,        // residual out (in-place ok)
                   const float* __restrict__ rin,  // residual in (= input at s0)
                   const float* __restrict__ cb,
                   const float* __restrict__ cb_sq,
                   float* __restrict__ rsq,        // in: this stage; out: next
                   const float* __restrict__ part,
                   const unsigned long long* __restrict__ gbuf,
                   float* __restrict__ qout,
                   float* __restrict__ idx_out,
                   unsigned short* __restrict__ rh,
                   int stage, int do_next) {
#pragma clang fp contract(off)
    const int t   = threadIdx.x;
    const int jr  = t & 31;                  // tile index / lane-in-group
    const int rs  = t >> 5;                  // 0..7
    const int row = blockIdx.x * 8 + rs;

    float pv = part[(size_t)jr * N_ROWS + row];
    float m = pv;
#pragma unroll
    for (int off = 1; off < 32; off <<= 1)
        m = fminf(m, __shfl_xor(m, off, 32));
    const float thr = m + EPS;

    unsigned long long s0 = EMPTY_E, s1 = EMPTY_E;
    bool surv = (pv <= thr);
    if (surv) {
        size_t bidx = ((size_t)jr * N_ROWS + row) * CAP;
        s0 = gbuf[bidx];
        s1 = gbuf[bidx + 1];
    }
    const bool ovfl = surv && (s0 == OVFL_E);

    int lcl = 0;
    unsigned long long cand = EMPTY_E;
    float y0 = __uint_as_float((unsigned)(s0 >> 32));   // EMPTY/OVFL -> NaN
    float y1 = __uint_as_float((unsigned)(s1 >> 32));
    if (surv && !ovfl) {
        if (y0 <= thr) { lcl++; cand = s0; }
        if (y1 <= thr) { lcl++; cand = s1; }
    }
    int tot = lcl;
    int oc  = ovfl ? 1 : 0;
#pragma unroll
    for (int off = 1; off < 32; off <<= 1) {
        tot += __shfl_xor(tot, off, 32);
        oc  += __shfl_xor(oc, off, 32);
    }

    const float* rr  = rin + (size_t)row * DIM;
    const float rsqv = rsq[row];

    unsigned long long lpk;
    if (tot == 1 && oc == 0) {
        lpk = (lcl == 1) ? cand : EMPTY_E;   // unique candidate == argmin
    } else {
        float by = INFINITY; int bk = 0x7fffffff;
        if (surv && !ovfl && lcl > 0) {
#pragma unroll
            for (int sl = 0; sl < CAP; ++sl) {
                unsigned long long s = sl ? s1 : s0;
                float yh = __uint_as_float((unsigned)(s >> 32));
                if (!(yh <= thr)) continue;  // EMPTY -> NaN -> skipped
                int k = (int)(s & 0xFFFFFFFFull);
                const float* wp = cb + (size_t)k * DIM;
                float dot = 0.0f;            // exact chain, d ascending
#pragma unroll 8
                for (int d = 0; d < DIM; d += 4) {
                    float4 r4 = *(const float4*)(rr + d);
                    float4 w4 = *(const float4*)(wp + d);
                    dot = fmaf(r4.x, w4.x, dot);
                    dot = fmaf(r4.y, w4.y, dot);
                    dot = fmaf(r4.z, w4.z, dot);
                    dot = fmaf(r4.w, w4.w, dot);
                }
                float t2 = 2.0f * dot;
                float u  = rsqv - t2;
                float y  = u + cb_sq[k];
                if (y < by || (y == by && k < bk)) { by = y; bk = k; }
            }
        }
        // Overflow tiles: full-tile exact recheck by the whole 32-lane group.
        unsigned grp = (unsigned)(__ballot(ovfl) >> (t & 32));
        while (grp) {
            int jt = __builtin_ctz(grp);
            grp &= grp - 1;
#pragma unroll
            for (int q = 0; q < 4; ++q) {
                int k = jt * 128 + jr * 4 + q;
                const float* wp = cb + (size_t)k * DIM;
                float dot = 0.0f;            // exact chain, d ascending
#pragma unroll 8
                for (int d = 0; d < DIM; d += 4) {
                    float4 r4 = *(const float4*)(rr + d);
                    float4 w4 = *(const float4*)(wp + d);
                    dot = fmaf(r4.x, w4.x, dot);
                    dot = fmaf(r4.y, w4.y, dot);
                    dot = fmaf(r4.z, w4.z, dot);
                    dot = fmaf(r4.w, w4.w, dot);
                }
                float t2 = 2.0f * dot;
                float u  = rsqv - t2;
                float y  = u + cb_sq[k];
                if (y < by || (y == by && k < bk)) { by = y; bk = k; }
            }
        }
        lpk = ((unsigned long long)__float_as_uint(by) << 32) | (unsigned)bk;
    }

    // Width-32 lexicographic min; butterfly -> ALL lanes hold the result.
#pragma unroll
    for (int off = 1; off < 32; off <<= 1) {
        unsigned long long o =
            (unsigned long long)__shfl_xor((long long)lpk, off, 32);
        if (o < lpk) lpk = o;
    }
    const int bi = (int)(lpk & 0xFFFFFFFFull);
    if (jr == 0) idx_out[(size_t)row * NUM_STAGES + stage] = (float)bi;

    // Fused combine (float4): lane jr owns d = 4*jr + 128*i, i = 0..3.
    const float* wp = cb + (size_t)bi * DIM;
    float*       rp = res + (size_t)row * DIM;
    float*       qp = qout + (size_t)row * DIM;
    unsigned short* rhp = rh + (size_t)row * DIM;

    float4 rn4[4];
#pragma unroll
    for (int i = 0; i < 4; ++i) {
        int d0 = 4 * jr + 128 * i;
        float4 wv = *(const float4*)(wp + d0);
        float4 rv = *(const float4*)(rr + d0);
        float4 qs, rn;
        qs.x = rv.x + (wv.x - rv.x);  rn.x = rv.x - qs.x;
        qs.y = rv.y + (wv.y - rv.y);  rn.y = rv.y - qs.y;
        qs.z = rv.z + (wv.z - rv.z);  rn.z = rv.z - qs.z;
        qs.w = rv.w + (wv.w - rv.w);  rn.w = rv.w - qs.w;
        rn4[i] = rn;
        if (do_next) {
            *(float4*)(rp + d0) = rn;
            ushort4 h;
            h.x = f2bf(rn.x); h.y = f2bf(rn.y);
            h.z = f2bf(rn.z); h.w = f2bf(rn.w);
            *(ushort4*)(rhp + d0) = h;
        }
        if (stage == 0) {
            *(float4*)(qp + d0) = qs;
        } else {
            float4 qo = *(const float4*)(qp + d0);
            qo.x = qo.x + qs.x; qo.y = qo.y + qs.y;
            qo.z = qo.z + qs.z; qo.w = qo.w + qs.w;
            *(float4*)(qp + d0) = qo;
        }
    }

    if (do_next) {
        // 32-lane float4-mapping numpy pairwise tree. Lane jr holds positions
        // p = b*128 + 4*jr + c. Addition DAG identical to the 64-lane tree:
        //   R[l]=sq[l]+sq[64+l]      : shfl_down 16 lanes (p-dist 64)
        //   t[l]=R[l]+R[l+16]        : shfl_down 4
        //   u[l]=t[l]+t[l+32]        : shfl_down 8
        //   a[l]=u[l]+u[l+8]         : shfl_down 2
        //   c[l]=a[l]+a[l+4]         : shfl_down 1
        //   d[l]=c[l]+c[l+2]         : components x+z, y+w
        //   P   =d[0]+d[1]
        float P[4];
#pragma unroll
        for (int b = 0; b < 4; ++b) {
            float4 v = rn4[b];
            float sqx = v.x * v.x, sqy = v.y * v.y;
            float sqz = v.z * v.z, sqw = v.w * v.w;
            float Rx = sqx + __shfl_down(sqx, 16, 32);
            float Ry = sqy + __shfl_down(sqy, 16, 32);
            float Rz = sqz + __shfl_down(sqz, 16, 32);
            float Rw = sqw + __shfl_down(sqw, 16, 32);
            float tx = Rx + __shfl_down(Rx, 4, 32);
            float ty = Ry + __shfl_down(Ry, 4, 32);
            float tz = Rz + __shfl_down(Rz, 4, 32);
            float tw = Rw + __shfl_down(Rw, 4, 32);
            float ux = tx + __shfl_down(tx, 8, 32);
            float uy = ty + __shfl_down(ty, 8, 32);
            float uz = tz + __shfl_down(tz, 8, 32);
            float uw = tw + __shfl_down(tw, 8, 32);
            float ax = ux + __shfl_down(ux, 2, 32);
            float ay = uy + __shfl_down(uy, 2, 32);
            float az = uz + __shfl_down(uz, 2, 32);
            float aw = uw + __shfl_down(uw, 2, 32);
            float cx = ax + __shfl_down(ax, 1, 32);
            float cy = ay + __shfl_down(ay, 1, 32);
            float cz = az + __shfl_down(az, 1, 32);
            float cw = aw + __shfl_down(aw, 1, 32);
            float d0 = cx + cz;
            float d1 = cy + cw;
            P[b] = d0 + d1;
        }
        float s01 = P[0] + P[1];
        float s23 = P[2] + P[3];
        if (jr == 0) rsq[row] = s01 + s23;
    }
}

extern "C" void kernel_launch(void* const* d_in, const int* in_sizes, int n_in,
                              void* d_out, int out_size, void* d_ws, size_t ws_size,
                              hipStream_t stream) {
    const float* input = (const float*)d_in[0];
    const float* cb    = (const float*)d_in[1];

    float* out_f   = (float*)d_out;
    float* qout    = out_f + Q_OFF;
    float* idx_out = out_f + IDX_OFF;
    float* loss    = out_f + LOSS_OFF;

    char* ws = (char*)d_ws;
    float*          residual = (float*)(ws + RES_OFF);
    unsigned short* rh       = (unsigned short*)(ws + RH_OFF);
    unsigned short* wh       = (unsigned short*)(ws + WH_OFF);
    float*          cb_sq    = (float*)(ws + CBSQ_OFF);
    float*          rsq      = (float*)(ws + RSQ_OFF);
    float*          part     = (float*)(ws + PART_OFF);
    unsigned long long* gbuf = (unsigned long long*)(ws + GBUF_OFF);

    cbsq_wh_kernel<<<K_CODES, 64, 0, stream>>>(cb, cb_sq, wh, loss);
    init_kernel<<<N_ROWS / 4, 256, 0, stream>>>(input, rh, rsq);

    for (int s = 0; s < NUM_STAGES; ++s) {
        const float* rin = (s == 0) ? input : residual;
        passA_kernel<<<dim3(KTILES, N_ROWS / 128), 256, 0, stream>>>(
            rh, wh, cb_sq, rsq, part, gbuf);
        finish_kernel<<<N_ROWS / 8, 256, 0, stream>>>(
            residual, rin, cb, cb_sq, rsq, part, gbuf,
            qout, idx_out, rh, s, (s < NUM_STAGES - 1) ? 1 : 0);
    }
}